// Round 1
// baseline (3118.302 us; speedup 1.0000x reference)
//
#include <hip/hip_runtime.h>
#include <hip/hip_bf16.h>
#include <stdint.h>

#define LSEQ 512
#define NB   64
#define IMGD 3200
#define EMBD 300
#define HD   256

typedef __bf16 bf16x8 __attribute__((ext_vector_type(8)));
typedef float  f32x4  __attribute__((ext_vector_type(4)));

__device__ __forceinline__ unsigned short f2bf(float x) {
  unsigned u = __builtin_bit_cast(unsigned, x);
  u = (u + 0x7FFFu + ((u >> 16) & 1u)) >> 16;
  return (unsigned short)u;
}

// ---------------- K1: init flags/h0 + phrase embed ----------------
__global__ __launch_bounds__(256) void k1_init_emb(
    const float* __restrict__ phr, const float* __restrict__ Wp,
    const float* __restrict__ bp, float* __restrict__ emb,
    unsigned* __restrict__ hbuf, int* __restrict__ flags) {
  int tid = threadIdx.x, blk = blockIdx.x;
  int gid = blk * 256 + tid;
  if (gid < 8192)  // zero h_0 (64 x 128 packed bf16 pairs)
    __hip_atomic_store(hbuf + gid, 0u, __ATOMIC_RELAXED, __HIP_MEMORY_SCOPE_AGENT);
  if (gid < 64)
    __hip_atomic_store(flags + gid, 0, __ATOMIC_RELAXED, __HIP_MEMORY_SCOPE_AGENT);
  if (blk < 16) {
    int b = gid >> 6, f = gid & 63;
    float acc = bp[f];
    for (int k = 0; k < EMBD; ++k) acc += phr[b * EMBD + k] * Wp[k * 64 + f];
    emb[gid] = fmaxf(acc, 0.f);
  }
}

// ---------------- K2: img_fc + fuse (fp32, 32 rows/block) ----------------
__global__ __launch_bounds__(256) void k2_imgfuse(
    const float* __restrict__ img, const float* __restrict__ Wc,
    const float* __restrict__ bc, const float* __restrict__ emb,
    unsigned short* __restrict__ fuse) {
  __shared__ float sX[32 * 65];   // +1 pad: conflict-free x reads
  __shared__ float sW[64 * 64];
  int tid = threadIdx.x, blk = blockIdx.x;
  int r = tid & 31, g = tid >> 5;          // compute map: row, col-group of 8
  int rs = tid >> 3, cs = (tid & 7) * 8;   // staging map
  float acc[8];
#pragma unroll
  for (int j = 0; j < 8; ++j) acc[j] = 0.f;

  for (int k0 = 0; k0 < IMGD; k0 += 64) {
    const float* xsrc = img + (size_t)(blk * 32 + rs) * IMGD + k0 + cs;
    float4 v0 = *(const float4*)xsrc;
    float4 v1 = *(const float4*)(xsrc + 4);
    float* xd = sX + rs * 65 + cs;
    xd[0]=v0.x; xd[1]=v0.y; xd[2]=v0.z; xd[3]=v0.w;
    xd[4]=v1.x; xd[5]=v1.y; xd[6]=v1.z; xd[7]=v1.w;
    const float4* wsrc = (const float4*)(Wc + k0 * 64);
#pragma unroll
    for (int i = 0; i < 4; ++i) ((float4*)sW)[i * 256 + tid] = wsrc[i * 256 + tid];
    __syncthreads();
#pragma unroll 8
    for (int k = 0; k < 64; ++k) {
      float xv = sX[r * 65 + k];
      const float* wr = sW + k * 64 + g * 8;
      float4 wa = *(const float4*)wr;
      float4 wb = *(const float4*)(wr + 4);
      acc[0] += xv * wa.x; acc[1] += xv * wa.y; acc[2] += xv * wa.z; acc[3] += xv * wa.w;
      acc[4] += xv * wb.x; acc[5] += xv * wb.y; acc[6] += xv * wb.z; acc[7] += xv * wb.w;
    }
    __syncthreads();
  }
  int rowg = blk * 32 + r;
  int b = rowg >> 9;
  unsigned pk[4];
#pragma unroll
  for (int j2 = 0; j2 < 4; ++j2) {
    int c = g * 8 + j2 * 2;
    float v0 = fmaxf(acc[j2 * 2] + bc[c], 0.f) * emb[b * 64 + c];
    float v1 = fmaxf(acc[j2 * 2 + 1] + bc[c + 1], 0.f) * emb[b * 64 + c + 1];
    pk[j2] = (unsigned)f2bf(v0) | ((unsigned)f2bf(v1) << 16);
  }
  *(uint4*)(fuse + (size_t)rowg * 64 + g * 8) = make_uint4(pk[0], pk[1], pk[2], pk[3]);
}

// ---------------- K3: persistent LSTM ----------------
// 64 WGs = 4 batch-groups x 16 hidden-slices. WG owns 16 batches x 16 hidden
// units (64 gate cols). Wz slice (K=320: 256 Whh + 64 Wih) LDS-resident bf16,
// transposed [col][k], stride 328 (16B aligned, banks spread).
__global__ __launch_bounds__(256) void k3_lstm(
    const float* __restrict__ Wih, const float* __restrict__ bih,
    const float* __restrict__ Whh, const float* __restrict__ bhh,
    const unsigned short* __restrict__ fuse,
    unsigned* __restrict__ hbuf, int* __restrict__ flags,
    float* __restrict__ outfeats) {
  __shared__ __align__(16) unsigned short sWt[64 * 328];
  __shared__ __align__(16) unsigned short sZ[16 * 328];
  __shared__ float sG[4 * 256];
  __shared__ float sC[256];
  __shared__ float sB[64];
  int tid = threadIdx.x;
  int wg  = blockIdx.x;
  int grp = wg >> 4;           // batch group 0..3
  int j16 = wg & 15;           // hidden slice
  int b0  = grp * 16;
  int h0  = j16 * 16;
  int l = tid & 63, w = tid >> 6;

  // stage transposed weight slice, bf16
  for (int ii = 0; ii < 16; ++ii) {
    int cl  = w * 16 + ii;               // local col: gate w, unit ii
    int col = w * 256 + h0 + ii;         // global gate column
    for (int k = l; k < 320; k += 64) {
      float v = (k < 256) ? Whh[k * 1024 + col] : Wih[(k - 256) * 1024 + col];
      sWt[cl * 328 + k] = f2bf(v);
    }
  }
  if (tid < 64) {
    int col = (tid >> 4) * 256 + h0 + (tid & 15);
    sB[tid] = bih[col] + bhh[col];
  }
  sC[tid] = 0.f;
  __syncthreads();

  int m = l & 15, q = l >> 4;
  const unsigned short* za = sZ  + m * 328 + q * 8;
  const unsigned short* wb = sWt + (w * 16 + m) * 328 + q * 8;
  int bb = tid >> 4, jl = tid & 15;
  const int* myflags = flags + grp * 16;

  for (int step = 0; step < LSEQ; ++step) {
    // wait until all peers in this batch group published h_step
    if (tid < 16) {
      while (__hip_atomic_load(myflags + tid, __ATOMIC_RELAXED,
                               __HIP_MEMORY_SCOPE_AGENT) < step)
        __builtin_amdgcn_s_sleep(1);
    }
    __syncthreads();
    // load z = [h_step | x_step] into LDS
    {
      const unsigned* hsrc = hbuf + (step & 1) * 8192;
      unsigned* zd = (unsigned*)sZ;
#pragma unroll
      for (int i = 0; i < 8; ++i) {
        int idx = tid + i * 256;  // 16 rows x 128 u32
        int row = idx >> 7, c2 = idx & 127;
        unsigned v = __hip_atomic_load(hsrc + (b0 + row) * 128 + c2,
                                       __ATOMIC_RELAXED, __HIP_MEMORY_SCOPE_AGENT);
        zd[row * 164 + c2] = v;
      }
      const unsigned* xsrc = (const unsigned*)fuse;
#pragma unroll
      for (int i = 0; i < 2; ++i) {
        int idx = tid + i * 256;  // 16 rows x 32 u32
        int row = idx >> 5, c2 = idx & 31;
        zd[row * 164 + 128 + c2] = xsrc[((b0 + row) * 512 + step) * 32 + c2];
      }
    }
    __syncthreads();
    // gates tile: wave w -> gate w, C = z(16x320) @ Wt^T
    f32x4 acc = {0.f, 0.f, 0.f, 0.f};
#pragma unroll
    for (int k0 = 0; k0 < 320; k0 += 32) {
      bf16x8 a = *(const bf16x8*)(za + k0);
      bf16x8 b = *(const bf16x8*)(wb + k0);
      acc = __builtin_amdgcn_mfma_f32_16x16x32_bf16(a, b, acc, 0, 0, 0);
    }
#pragma unroll
    for (int r2 = 0; r2 < 4; ++r2)
      sG[w * 256 + (q * 4 + r2) * 16 + m] = acc[r2];
    __syncthreads();
    // pointwise cell update: thread = (batch bb, unit jl)
    float gi = sG[0 * 256 + tid] + sB[jl];
    float gf = sG[1 * 256 + tid] + sB[16 + jl];
    float gg = sG[2 * 256 + tid] + sB[32 + jl];
    float go = sG[3 * 256 + tid] + sB[48 + jl];
    float si = 1.f / (1.f + __expf(-gi));
    float sf = 1.f / (1.f + __expf(-gf));
    float so = 1.f / (1.f + __expf(-go));
    float e2g = __expf(2.f * gg);
    float tg = (e2g - 1.f) / (e2g + 1.f);
    float cn = sf * sC[tid] + si * tg;
    sC[tid] = cn;
    float e2c = __expf(2.f * cn);
    float hn = so * (e2c - 1.f) / (e2c + 1.f);
    __hip_atomic_store(outfeats + ((size_t)(b0 + bb) * LSEQ + step) * HD + h0 + jl,
                       hn, __ATOMIC_RELAXED, __HIP_MEMORY_SCOPE_AGENT);
    float hp = __shfl_xor(hn, 1);
    if ((tid & 1) == 0) {
      unsigned pk = (unsigned)f2bf(hn) | ((unsigned)f2bf(hp) << 16);
      __hip_atomic_store(hbuf + ((step + 1) & 1) * 8192 + (b0 + bb) * 128 +
                             ((h0 + jl) >> 1),
                         pk, __ATOMIC_RELAXED, __HIP_MEMORY_SCOPE_AGENT);
    }
    __syncthreads();  // per-wave vmcnt(0) drain: all WG stores performed
    if (tid == 0)
      __hip_atomic_store(flags + wg, step + 1, __ATOMIC_RELEASE,
                         __HIP_MEMORY_SCOPE_AGENT);
  }
}

// ---------------- K4: classifier + log_softmax ----------------
__global__ __launch_bounds__(256) void k4_classifier(
    const float* __restrict__ feats, const float* __restrict__ Wc1,
    const float* __restrict__ bc1, const float* __restrict__ Wc2,
    const float* __restrict__ bc2, float* __restrict__ lp) {
  __shared__ float sW[64 * 64];
  __shared__ float sX[16 * 257];
  __shared__ float sH[16 * 68];
  int tid = threadIdx.x, blk = blockIdx.x;
  {
    int rs = tid >> 4, seg = (tid & 15) * 16;
    const float4* src = (const float4*)(feats + (size_t)(blk * 16 + rs) * 256 + seg);
    float* xd = sX + rs * 257 + seg;
#pragma unroll
    for (int i = 0; i < 4; ++i) {
      float4 v = src[i];
      xd[i*4+0]=v.x; xd[i*4+1]=v.y; xd[i*4+2]=v.z; xd[i*4+3]=v.w;
    }
  }
  int r = tid & 15, g = tid >> 4;
  float acc[4] = {0.f, 0.f, 0.f, 0.f};
  for (int c4 = 0; c4 < 4; ++c4) {
    __syncthreads();
#pragma unroll
    for (int i = 0; i < 4; ++i)
      ((float4*)sW)[i * 256 + tid] = ((const float4*)(Wc1 + c4 * 4096))[i * 256 + tid];
    __syncthreads();
#pragma unroll 8
    for (int k = 0; k < 64; ++k) {
      float xv = sX[r * 257 + c4 * 64 + k];
      float4 wv = *(const float4*)(sW + k * 64 + g * 4);
      acc[0] += xv * wv.x; acc[1] += xv * wv.y; acc[2] += xv * wv.z; acc[3] += xv * wv.w;
    }
  }
#pragma unroll
  for (int j = 0; j < 4; ++j) {
    int c = g * 4 + j;
    sH[r * 68 + c] = fmaxf(acc[j] + bc1[c], 0.f);
  }
  __syncthreads();
  if (tid < 16) {
    float l0 = bc2[0], l1 = bc2[1];
    for (int c = 0; c < 64; ++c) {
      float h = sH[tid * 68 + c];
      l0 += h * Wc2[c * 2]; l1 += h * Wc2[c * 2 + 1];
    }
    float mx = fmaxf(l0, l1);
    float lse = mx + logf(__expf(l0 - mx) + __expf(l1 - mx));
    int rowg = blk * 16 + tid;
    lp[rowg * 2]     = l0 - lse;
    lp[rowg * 2 + 1] = l1 - lse;
  }
}

// ---------------- K5: gather selected ----------------
__global__ __launch_bounds__(256) void k5_select(
    const float* __restrict__ feats, const int* __restrict__ six,
    float* __restrict__ sel) {
  int b = blockIdx.x, tid = threadIdx.x;
  int ix = six[b];
  sel[b * 256 + tid] = feats[((size_t)b * 512 + ix) * 256 + tid];
}

extern "C" void kernel_launch(void* const* d_in, const int* in_sizes, int n_in,
                              void* d_out, int out_size, void* d_ws, size_t ws_size,
                              hipStream_t stream) {
  const float* img = (const float*)d_in[0];
  const float* phr = (const float*)d_in[1];
  // d_in[2] = masks (unused by reference)
  const int*   six = (const int*)d_in[3];
  const float* Wc  = (const float*)d_in[4];
  const float* bc  = (const float*)d_in[5];
  const float* Wp  = (const float*)d_in[6];
  const float* bp  = (const float*)d_in[7];
  const float* Wih = (const float*)d_in[8];
  const float* bih = (const float*)d_in[9];
  const float* Whh = (const float*)d_in[10];
  const float* bhh = (const float*)d_in[11];
  const float* Wc1 = (const float*)d_in[12];
  const float* bc1 = (const float*)d_in[13];
  const float* Wc2 = (const float*)d_in[14];
  const float* bc2 = (const float*)d_in[15];

  float* out_lp   = (float*)d_out;        // (64,512,2)
  float* out_feat = out_lp + 65536;       // (64,512,256)
  float* out_sel  = out_feat + 8388608;   // (64,256)

  char* ws = (char*)d_ws;
  float*          emb   = (float*)ws;                              // 16 KB
  unsigned short* fuse  = (unsigned short*)(ws + 16384);           // 4 MB bf16
  unsigned*       hbuf  = (unsigned*)(ws + 16384 + 4194304);       // 64 KB
  int*            flags = (int*)(ws + 16384 + 4194304 + 65536);    // 256 B

  hipLaunchKernelGGL(k1_init_emb, dim3(32), dim3(256), 0, stream,
                     phr, Wp, bp, emb, hbuf, flags);
  hipLaunchKernelGGL(k2_imgfuse, dim3(1024), dim3(256), 0, stream,
                     img, Wc, bc, emb, fuse);
  hipLaunchKernelGGL(k3_lstm, dim3(64), dim3(256), 0, stream,
                     Wih, bih, Whh, bhh, fuse, hbuf, flags, out_feat);
  hipLaunchKernelGGL(k4_classifier, dim3(2048), dim3(256), 0, stream,
                     out_feat, Wc1, bc1, Wc2, bc2, out_lp);
  hipLaunchKernelGGL(k5_select, dim3(64), dim3(256), 0, stream,
                     out_feat, six, out_sel);
}